// Round 5
// baseline (1068.849 us; speedup 1.0000x reference)
//
#include <hip/hip_runtime.h>
#include <hip/hip_bf16.h>
#include <stdint.h>

// ---- fixed problem geometry (GRID_N=41, deterministic) ----
#define NV1 1681
#define NF1 3200
#define NS1 (3*NF1)      // 9600 edge slots
#define NV2 6561
#define NF2 12800
#define NS2 (3*NF2)      // 38400 edge slots
#define NV3 25921
#define D1  1286         // valid cols: [verts(3) | perc1(1280) | verts(3)]
#define P1  1288         // padded row stride (16B aligned)
#define D2  2566         // valid cols: [verts2(3) | perc2(1280) | s2(1283)]
#define P2  2568         // padded row stride (16B aligned)
#define DOUT 3843        // [perc3(1280) | s3(2563)]
#define TSIZE 131072
#define TMASK (TSIZE-1)

// ---------------- feature transpose: in[R][Cc] -> out[Cc][R] ----------------
__global__ __launch_bounds__(256) void transpose32(
    const float* __restrict__ in, float* __restrict__ outp, int R, int Cc)
{
  __shared__ float tile[32][33];
  int bx = blockIdx.x * 32;   // col base (in)
  int by = blockIdx.y * 32;   // row base (in)
  int tx = threadIdx.x, ty = threadIdx.y;   // 32 x 8
  for (int j = ty; j < 32; j += 8) {
    int r = by + j, c = bx + tx;
    if (r < R && c < Cc) tile[j][tx] = in[(size_t)r*Cc + c];
  }
  __syncthreads();
  for (int j = ty; j < 32; j += 8) {
    int orow = bx + j, oc = by + tx;
    if (orow < Cc && oc < R) outp[(size_t)orow*R + oc] = tile[tx][j];
  }
}

// ---------------- shared pooling helper (channel-last features) ----------------
// thread `tid` in [0,320) handles 4 consecutive channels of one vertex.
// wave boundaries (c4 = 256, 768) are wave-uniform.
__device__ __forceinline__ void pool_row(
    int tid, float X, float Y, float Z,
    const float* __restrict__ t3, const float* __restrict__ t4,
    const float* __restrict__ t5, float* __restrict__ orow)
{
  float p2 = Z + 0.8f;
  float px = (248.0f*X + 111.5f*Z + 89.2f) / p2;
  float py = (248.0f*Y + 111.5f*Z + 89.2f) / p2;

  int c4 = tid * 4;
  int m  = (c4 < 256) ? 0 : (c4 < 768) ? 1 : 2;
  int dim = (m == 0) ? 56 : (m == 1) ? 28 : 14;
  int C   = (m == 0) ? 256 : 512;
  int cb  = (m == 0) ? 0 : (m == 1) ? 256 : 768;
  const float* t = (m == 0) ? t3 : (m == 1) ? t4 : t5;

  float dimf = (float)dim;
  float x = fminf(fmaxf(px * dimf / 224.0f, 0.0f), dimf - 1.0f);
  float y = fminf(fmaxf(py * dimf / 224.0f, 0.0f), dimf - 1.0f);
  float x1 = floorf(x), x2 = ceilf(x);
  float y1 = floorf(y), y2 = ceilf(y);
  int xi1 = min(max((int)x1, 0), dim-1);
  int xi2 = min(max((int)x2, 0), dim-1);
  int yi1 = min(max((int)y1, 0), dim-1);
  int yi2 = min(max((int)y2, 0), dim-1);
  float w11 = (x2-x)*(y2-y), w12 = (x2-x)*(y-y1);
  float w21 = (x-x1)*(y2-y), w22 = (x-x1)*(y-y1);

  int cc = c4 - cb;
  const float4 f11 = *(const float4*)(t + (size_t)(xi1*dim + yi1)*C + cc);
  const float4 f12 = *(const float4*)(t + (size_t)(xi1*dim + yi2)*C + cc);
  const float4 f21 = *(const float4*)(t + (size_t)(xi2*dim + yi1)*C + cc);
  const float4 f22 = *(const float4*)(t + (size_t)(xi2*dim + yi2)*C + cc);

  float* o = orow + c4;
  o[0] = w11*f11.x + w12*f12.x + w21*f21.x + w22*f22.x;
  o[1] = w11*f11.y + w12*f12.y + w21*f21.y + w22*f22.y;
  o[2] = w11*f11.z + w12*f12.z + w21*f21.z + w22*f22.z;
  o[3] = w11*f11.w + w12*f12.w + w21*f21.w + w22*f22.w;
}

// ---------------- level-1: pool verts + scatter verts copies into vf1 ----------
__global__ __launch_bounds__(320) void pool1f(
    const float* __restrict__ verts,
    const float* __restrict__ t3, const float* __restrict__ t4,
    const float* __restrict__ t5, float* __restrict__ vf1)
{
  int v = blockIdx.x;
  int tid = (int)threadIdx.x;
  float X = verts[3*v+0], Y = verts[3*v+1], Z = verts[3*v+2];
  if (tid < 3) {
    float w = verts[3*v + tid];
    vf1[(size_t)v*P1 + tid] = w;
    vf1[(size_t)v*P1 + 1283 + tid] = w;
  }
  pool_row(tid, X, Y, Z, t3, t4, t5, vf1 + (size_t)v*P1 + 3);
}

// ---------------- connectivity: one block does everything for one level -------
// Replicates np.unique first-occurrence ranking of undirected edges.
// phases: insert (CAS+atomicMin) -> first-count -> ladder scan ->
//         write rank into table slot -> mid lookup -> (optional) new_faces
__global__ __launch_bounds__(1024) void connectivity(
    const int* __restrict__ faces, int F, int V,
    unsigned* __restrict__ tkey, unsigned* __restrict__ tmin,
    unsigned* __restrict__ keys,
    int* __restrict__ mid, int* __restrict__ uea, int* __restrict__ ueb,
    int* __restrict__ nf)
{
  int S = 3*F;
  int tid = (int)threadIdx.x;
  // phase 1: insert every edge slot
  for (int s = tid; s < S; s += 1024) {
    int f = s/3, k = s - 3*f;
    int a0 = faces[3*f + k];
    int a1 = faces[3*f + (k == 2 ? 0 : k+1)];
    int a = min(a0, a1), b = max(a0, a1);
    unsigned key = (unsigned)a * (unsigned)V + (unsigned)b;
    keys[s] = key;
    unsigned h = (key * 2654435761u) & TMASK;
    while (true) {
      unsigned old = atomicCAS(&tkey[h], 0xFFFFFFFFu, key);
      if (old == 0xFFFFFFFFu || old == key) { atomicMin(&tmin[h], (unsigned)s); break; }
      h = (h+1) & TMASK;
    }
  }
  __syncthreads();
  // phase 2: blocked ranges, count first occurrences
  __shared__ int tmp[1024];
  int npt = (S + 1023) >> 10;
  int base = tid * npt;
  int end = min(base + npt, S);
  int cnt = 0;
  for (int i = base; i < end; ++i) {
    unsigned key = keys[i];
    unsigned h = (key * 2654435761u) & TMASK;
    while (tkey[h] != key) h = (h+1) & TMASK;
    if ((int)tmin[h] == i) cnt++;
  }
  tmp[tid] = cnt;
  __syncthreads();
  for (int off = 1; off < 1024; off <<= 1) {
    int t = (tid >= off) ? tmp[tid - off] : 0;
    __syncthreads();
    tmp[tid] += t;
    __syncthreads();
  }
  int run = tmp[tid] - cnt;   // exclusive offset of this thread's range
  // phase 3a: firsts write their rank into the table slot (tmin reused) + ue lists
  for (int i = base; i < end; ++i) {
    unsigned key = keys[i];
    unsigned h = (key * 2654435761u) & TMASK;
    while (tkey[h] != key) h = (h+1) & TMASK;
    if ((int)tmin[h] == i) {
      uea[run] = (int)(key / (unsigned)V);
      ueb[run] = (int)(key % (unsigned)V);
      tmin[h] = (unsigned)run;   // safe: every slot read in 3a before any rewrite?  No:
      run++;                     // tmin[h] is read (phase2-style) only for THIS i == first,
    }                            // and each first has a unique slot h, so no cross-talk.
  }
  __syncthreads();
  // phase 3b: all slots look up rank
  for (int i = base; i < end; ++i) {
    unsigned key = keys[i];
    unsigned h = (key * 2654435761u) & TMASK;
    while (tkey[h] != key) h = (h+1) & TMASK;
    mid[i] = V + (int)tmin[h];
  }
  if (nf) {
    __syncthreads();
    // phase 4: emit subdivided faces
    for (int f = tid; f < F; f += 1024) {
      int i1 = faces[3*f], i2 = faces[3*f+1], i3 = faces[3*f+2];
      int i4 = mid[3*f], i5 = mid[3*f+1], i6 = mid[3*f+2];
      int* o = nf + 12*f;
      o[0]=i1; o[1]=i4; o[2]=i6;
      o[3]=i2; o[4]=i4; o[5]=i5;
      o[6]=i3; o[7]=i5; o[8]=i6;
      o[9]=i5; o[10]=i4; o[11]=i6;
    }
  }
}

// ---------------- fused subdivide + pool: one block per output row ------------
// subdivide src row (copy or edge-midpoint) into [dstV cols 0:3 | dstS cols 3:Dsub],
// stash verts in LDS, then pool them into dstP.
__global__ __launch_bounds__(512) void subpool(
    const float* __restrict__ src, int P, int Dsub, int Vold,
    const int* __restrict__ uea, const int* __restrict__ ueb,
    const float* __restrict__ t3, const float* __restrict__ t4,
    const float* __restrict__ t5,
    float* __restrict__ dstV, int dvs,
    float* __restrict__ dstS, int dss,
    float* __restrict__ dstP, int dps)
{
  __shared__ float sv[3];
  int r = blockIdx.x;
  int tid = (int)threadIdx.x;
  bool isCopy = (r < Vold);
  int a = 0, b = 0;
  if (!isCopy) { int e = r - Vold; a = uea[e]; b = ueb[e]; }
  for (int c4 = 4*tid; c4 < Dsub; c4 += 4*512) {
    float4 val;
    if (isCopy) {
      val = *(const float4*)(src + (size_t)r*P + c4);
    } else {
      float4 va = *(const float4*)(src + (size_t)a*P + c4);
      float4 vb = *(const float4*)(src + (size_t)b*P + c4);
      val.x = 0.5f*(va.x+vb.x); val.y = 0.5f*(va.y+vb.y);
      val.z = 0.5f*(va.z+vb.z); val.w = 0.5f*(va.w+vb.w);
    }
    float vv[4] = {val.x, val.y, val.z, val.w};
#pragma unroll
    for (int t = 0; t < 4; ++t) {
      int c = c4 + t;
      if (c >= Dsub) break;
      float x = vv[t];
      if (c < 3) {
        sv[c] = x;
        if (dstV) dstV[(size_t)r*dvs + c] = x;
      } else {
        dstS[(size_t)r*dss + (c-3)] = x;
      }
    }
  }
  __syncthreads();
  if (tid < 320)
    pool_row(tid, sv[0], sv[1], sv[2], t3, t4, t5, dstP + (size_t)r*dps);
}

// ---------------- host ----------------
static inline char* bump(char*& p, size_t bytes) {
  char* r = p;
  p += (bytes + 255) & ~(size_t)255;
  return r;
}

extern "C" void kernel_launch(void* const* d_in, const int* in_sizes, int n_in,
                              void* d_out, int out_size, void* d_ws, size_t ws_size,
                              hipStream_t stream)
{
  const float* f3    = (const float*)d_in[0];
  const float* f4    = (const float*)d_in[1];
  const float* f5    = (const float*)d_in[2];
  const float* verts = (const float*)d_in[3];
  const int*   faces = (const int*)d_in[4];
  float* out = (float*)d_out;

  char* p = (char*)d_ws;
  float* t3     = (float*)bump(p, (size_t)3136*256*4);
  float* t4     = (float*)bump(p, (size_t)784*512*4);
  float* t5     = (float*)bump(p, (size_t)196*512*4);
  float* vf1    = (float*)bump(p, (size_t)NV1*P1*4);
  float* vf2    = (float*)bump(p, (size_t)NV2*P2*4);
  int*   faces2 = (int*)  bump(p, (size_t)NF2*3*4);
  unsigned* key1 = (unsigned*)bump(p, (size_t)NS1*4);
  int* mid1   = (int*)bump(p, (size_t)NS1*4);
  int* ue1a   = (int*)bump(p, (size_t)NS1*4);
  int* ue1b   = (int*)bump(p, (size_t)NS1*4);
  unsigned* key2 = (unsigned*)bump(p, (size_t)NS2*4);
  int* mid2   = (int*)bump(p, (size_t)NS2*4);
  int* ue2a   = (int*)bump(p, (size_t)NS2*4);
  int* ue2b   = (int*)bump(p, (size_t)NS2*4);
  // 4 contiguous tables -> one 0xFF memset (tmin is unsigned, init = UINT_MAX)
  unsigned* tables = (unsigned*)bump(p, (size_t)4*TSIZE*4);
  unsigned* tkey1 = tables;
  unsigned* tmin1 = tables + TSIZE;
  unsigned* tkey2 = tables + 2*TSIZE;
  unsigned* tmin2 = tables + 3*TSIZE;

  hipMemsetAsync(tables, 0xFF, (size_t)4*TSIZE*4, stream);

  // ---- feature transpose to channel-last: t[pos][c] ----
  transpose32<<<dim3((3136+31)/32, (256+31)/32), dim3(32,8), 0, stream>>>(f3, t3, 256, 3136);
  transpose32<<<dim3(( 784+31)/32, (512+31)/32), dim3(32,8), 0, stream>>>(f4, t4, 512,  784);
  transpose32<<<dim3(( 196+31)/32, (512+31)/32), dim3(32,8), 0, stream>>>(f5, t5, 512,  196);

  // ---- level 1: vf1 = [verts | perc1 | verts] ----
  pool1f<<<NV1, 320, 0, stream>>>(verts, t3, t4, t5, vf1);
  connectivity<<<1, 1024, 0, stream>>>(faces, NF1, NV1, tkey1, tmin1,
                                       key1, mid1, ue1a, ue1b, faces2);

  // ---- level 2: vf2 = [verts2(0:3) | perc2(3:1283) | s2(1283:2566)] ----
  subpool<<<NV2, 512, 0, stream>>>(vf1, P1, D1, NV1, ue1a, ue1b, t3, t4, t5,
                                   vf2, P2, vf2 + 1283, P2, vf2 + 3, P2);
  connectivity<<<1, 1024, 0, stream>>>(faces2, NF2, NV2, tkey2, tmin2,
                                       key2, mid2, ue2a, ue2b, nullptr);

  // ---- level 3: out = [perc3(0:1280) | s3(1280:3843)] ----
  subpool<<<NV3, 512, 0, stream>>>(vf2, P2, D2, NV2, ue2a, ue2b, t3, t4, t5,
                                   nullptr, 0, out + 1280, DOUT, out, DOUT);
}

// Round 6
// 636.730 us; speedup vs baseline: 1.6787x; 1.6787x over previous
//
#include <hip/hip_runtime.h>
#include <hip/hip_bf16.h>
#include <stdint.h>

// ---- fixed problem geometry (GRID_N=41, deterministic) ----
#define NV1 1681
#define NF1 3200
#define NS1 (3*NF1)      // 9600 edge slots
#define NV2 6561
#define NF2 12800
#define NS2 (3*NF2)      // 38400 edge slots
#define NV3 25921
#define D1  1286         // valid cols: [verts(3) | perc1(1280) | verts(3)]
#define P1  1288         // padded row stride (16B aligned)
#define D2  2566         // valid cols: [verts2(3) | perc2(1280) | s2(1283)]
#define P2  2568         // padded row stride (16B aligned)
#define DOUT 3843        // [perc3(1280) | s3(2563)]
#define TSIZE 131072
#define TMASK (TSIZE-1)

// ---------------- feature transpose: in[R][Cc] -> out[Cc][R] ----------------
__global__ __launch_bounds__(256) void transpose32(
    const float* __restrict__ in, float* __restrict__ outp, int R, int Cc)
{
  __shared__ float tile[32][33];
  int bx = blockIdx.x * 32;   // col base (in)
  int by = blockIdx.y * 32;   // row base (in)
  int tx = threadIdx.x, ty = threadIdx.y;   // 32 x 8
  for (int j = ty; j < 32; j += 8) {
    int r = by + j, c = bx + tx;
    if (r < R && c < Cc) tile[j][tx] = in[(size_t)r*Cc + c];
  }
  __syncthreads();
  for (int j = ty; j < 32; j += 8) {
    int orow = bx + j, oc = by + tx;
    if (orow < Cc && oc < R) outp[(size_t)orow*R + oc] = tile[tx][j];
  }
}

// ---------------- shared pooling helper (channel-last features) ----------------
// thread `tid` in [0,320) handles 4 consecutive channels of one vertex.
// wave boundaries (c4 = 256, 768) are wave-uniform.
__device__ __forceinline__ void pool_row(
    int tid, float X, float Y, float Z,
    const float* __restrict__ t3, const float* __restrict__ t4,
    const float* __restrict__ t5, float* __restrict__ orow)
{
  float p2 = Z + 0.8f;
  float px = (248.0f*X + 111.5f*Z + 89.2f) / p2;
  float py = (248.0f*Y + 111.5f*Z + 89.2f) / p2;

  int c4 = tid * 4;
  int m  = (c4 < 256) ? 0 : (c4 < 768) ? 1 : 2;
  int dim = (m == 0) ? 56 : (m == 1) ? 28 : 14;
  int C   = (m == 0) ? 256 : 512;
  int cb  = (m == 0) ? 0 : (m == 1) ? 256 : 768;
  const float* t = (m == 0) ? t3 : (m == 1) ? t4 : t5;

  float dimf = (float)dim;
  float x = fminf(fmaxf(px * dimf / 224.0f, 0.0f), dimf - 1.0f);
  float y = fminf(fmaxf(py * dimf / 224.0f, 0.0f), dimf - 1.0f);
  float x1 = floorf(x), x2 = ceilf(x);
  float y1 = floorf(y), y2 = ceilf(y);
  int xi1 = min(max((int)x1, 0), dim-1);
  int xi2 = min(max((int)x2, 0), dim-1);
  int yi1 = min(max((int)y1, 0), dim-1);
  int yi2 = min(max((int)y2, 0), dim-1);
  float w11 = (x2-x)*(y2-y), w12 = (x2-x)*(y-y1);
  float w21 = (x-x1)*(y2-y), w22 = (x-x1)*(y-y1);

  int cc = c4 - cb;
  const float4 f11 = *(const float4*)(t + (size_t)(xi1*dim + yi1)*C + cc);
  const float4 f12 = *(const float4*)(t + (size_t)(xi1*dim + yi2)*C + cc);
  const float4 f21 = *(const float4*)(t + (size_t)(xi2*dim + yi1)*C + cc);
  const float4 f22 = *(const float4*)(t + (size_t)(xi2*dim + yi2)*C + cc);

  float* o = orow + c4;
  o[0] = w11*f11.x + w12*f12.x + w21*f21.x + w22*f22.x;
  o[1] = w11*f11.y + w12*f12.y + w21*f21.y + w22*f22.y;
  o[2] = w11*f11.z + w12*f12.z + w21*f21.z + w22*f22.z;
  o[3] = w11*f11.w + w12*f12.w + w21*f21.w + w22*f22.w;
}

// ---------------- level-1: pool verts + scatter verts copies into vf1 ----------
__global__ __launch_bounds__(320) void pool1f(
    const float* __restrict__ verts,
    const float* __restrict__ t3, const float* __restrict__ t4,
    const float* __restrict__ t5, float* __restrict__ vf1)
{
  int v = blockIdx.x;
  int tid = (int)threadIdx.x;
  float X = verts[3*v+0], Y = verts[3*v+1], Z = verts[3*v+2];
  if (tid < 3) {
    float w = verts[3*v + tid];
    vf1[(size_t)v*P1 + tid] = w;
    vf1[(size_t)v*P1 + 1283 + tid] = w;
  }
  pool_row(tid, X, Y, Z, t3, t4, t5, vf1 + (size_t)v*P1 + 3);
}

// ---------------- connectivity (multi-block; replicates np.unique ranks) ------
__global__ void edge_insert(const int* __restrict__ faces, int F, int V,
                            unsigned* __restrict__ tkey, unsigned* __restrict__ tmin,
                            unsigned* __restrict__ keys)
{
  int s = blockIdx.x*blockDim.x + threadIdx.x;
  if (s >= 3*F) return;
  int f = s/3, k = s - 3*f;
  int a0 = faces[3*f + k];
  int a1 = faces[3*f + (k == 2 ? 0 : k+1)];
  int a = min(a0, a1), b = max(a0, a1);
  unsigned key = (unsigned)a * (unsigned)V + (unsigned)b;
  keys[s] = key;
  unsigned h = (key * 2654435761u) & TMASK;
  while (true) {
    unsigned old = atomicCAS(&tkey[h], 0xFFFFFFFFu, key);
    if (old == 0xFFFFFFFFu || old == key) { atomicMin(&tmin[h], (unsigned)s); break; }
    h = (h+1) & TMASK;
  }
}

__global__ void edge_first(const unsigned* __restrict__ keys, int S,
                           const unsigned* __restrict__ tkey, const unsigned* __restrict__ tmin,
                           int* __restrict__ fslot)
{
  int s = blockIdx.x*blockDim.x + threadIdx.x;
  if (s >= S) return;
  unsigned key = keys[s];
  unsigned h = (key * 2654435761u) & TMASK;
  while (tkey[h] != key) h = (h+1) & TMASK;
  fslot[s] = (int)tmin[h];
}

// exclusive prefix sum of (fslot[i]==i): per-thread sequential + one ladder scan
__global__ __launch_bounds__(1024) void scan_excl(const int* __restrict__ fslot,
                                                  int* __restrict__ ranks, int n)
{
  __shared__ int tmp[1024];
  int tid = (int)threadIdx.x;
  int npt = (n + 1023) >> 10;
  int base = tid * npt;
  int cnt = 0;
  for (int j = 0; j < npt; ++j) {
    int i = base + j;
    if (i < n && fslot[i] == i) cnt++;
  }
  tmp[tid] = cnt;
  __syncthreads();
  for (int off = 1; off < 1024; off <<= 1) {
    int t = (tid >= off) ? tmp[tid - off] : 0;
    __syncthreads();
    tmp[tid] += t;
    __syncthreads();
  }
  int run = tmp[tid] - cnt;   // exclusive offset
  for (int j = 0; j < npt; ++j) {
    int i = base + j;
    if (i < n) { ranks[i] = run; if (fslot[i] == i) run++; }
  }
}

__global__ void edge_mid(const unsigned* __restrict__ keys, const int* __restrict__ fslot,
                         const int* __restrict__ ranks, int S, int V,
                         int* __restrict__ mid, int* __restrict__ uea, int* __restrict__ ueb)
{
  int s = blockIdx.x*blockDim.x + threadIdx.x;
  if (s >= S) return;
  int fs = fslot[s];
  int r = ranks[fs];
  mid[s] = V + r;
  if (fs == s) {
    unsigned key = keys[s];
    uea[r] = (int)(key / (unsigned)V);
    ueb[r] = (int)(key % (unsigned)V);
  }
}

__global__ void new_faces(const int* __restrict__ faces, int F,
                          const int* __restrict__ mid, int* __restrict__ nf)
{
  int f = blockIdx.x*blockDim.x + threadIdx.x;
  if (f >= F) return;
  int i1 = faces[3*f], i2 = faces[3*f+1], i3 = faces[3*f+2];
  int i4 = mid[3*f], i5 = mid[3*f+1], i6 = mid[3*f+2];
  int* o = nf + 12*f;
  o[0]=i1; o[1]=i4; o[2]=i6;
  o[3]=i2; o[4]=i4; o[5]=i5;
  o[6]=i3; o[7]=i5; o[8]=i6;
  o[9]=i5; o[10]=i4; o[11]=i6;
}

// ---------------- fused subdivide + pool: one block per output row ------------
// subdivide src row (copy or edge-midpoint) into [dstV cols 0:3 | dstS cols 3:Dsub],
// stash verts in LDS, then pool them into dstP.
__global__ __launch_bounds__(512) void subpool(
    const float* __restrict__ src, int P, int Dsub, int Vold,
    const int* __restrict__ uea, const int* __restrict__ ueb,
    const float* __restrict__ t3, const float* __restrict__ t4,
    const float* __restrict__ t5,
    float* __restrict__ dstV, int dvs,
    float* __restrict__ dstS, int dss,
    float* __restrict__ dstP, int dps)
{
  __shared__ float sv[3];
  int r = blockIdx.x;
  int tid = (int)threadIdx.x;
  bool isCopy = (r < Vold);
  int a = 0, b = 0;
  if (!isCopy) { int e = r - Vold; a = uea[e]; b = ueb[e]; }
  for (int c4 = 4*tid; c4 < Dsub; c4 += 4*512) {
    float4 val;
    if (isCopy) {
      val = *(const float4*)(src + (size_t)r*P + c4);
    } else {
      float4 va = *(const float4*)(src + (size_t)a*P + c4);
      float4 vb = *(const float4*)(src + (size_t)b*P + c4);
      val.x = 0.5f*(va.x+vb.x); val.y = 0.5f*(va.y+vb.y);
      val.z = 0.5f*(va.z+vb.z); val.w = 0.5f*(va.w+vb.w);
    }
    float vv[4] = {val.x, val.y, val.z, val.w};
#pragma unroll
    for (int t = 0; t < 4; ++t) {
      int c = c4 + t;
      if (c >= Dsub) break;
      float x = vv[t];
      if (c < 3) {
        sv[c] = x;
        if (dstV) dstV[(size_t)r*dvs + c] = x;
      } else {
        dstS[(size_t)r*dss + (c-3)] = x;
      }
    }
  }
  __syncthreads();
  if (tid < 320)
    pool_row(tid, sv[0], sv[1], sv[2], t3, t4, t5, dstP + (size_t)r*dps);
}

// ---------------- host ----------------
static inline char* bump(char*& p, size_t bytes) {
  char* r = p;
  p += (bytes + 255) & ~(size_t)255;
  return r;
}

extern "C" void kernel_launch(void* const* d_in, const int* in_sizes, int n_in,
                              void* d_out, int out_size, void* d_ws, size_t ws_size,
                              hipStream_t stream)
{
  const float* f3    = (const float*)d_in[0];
  const float* f4    = (const float*)d_in[1];
  const float* f5    = (const float*)d_in[2];
  const float* verts = (const float*)d_in[3];
  const int*   faces = (const int*)d_in[4];
  float* out = (float*)d_out;

  char* p = (char*)d_ws;
  float* t3     = (float*)bump(p, (size_t)3136*256*4);
  float* t4     = (float*)bump(p, (size_t)784*512*4);
  float* t5     = (float*)bump(p, (size_t)196*512*4);
  float* vf1    = (float*)bump(p, (size_t)NV1*P1*4);
  float* vf2    = (float*)bump(p, (size_t)NV2*P2*4);
  int*   faces2 = (int*)  bump(p, (size_t)NF2*3*4);
  unsigned* key1 = (unsigned*)bump(p, (size_t)NS1*4);
  int* fslot1 = (int*)bump(p, (size_t)NS1*4);
  int* rank1  = (int*)bump(p, (size_t)NS1*4);
  int* mid1   = (int*)bump(p, (size_t)NS1*4);
  int* ue1a   = (int*)bump(p, (size_t)NS1*4);
  int* ue1b   = (int*)bump(p, (size_t)NS1*4);
  unsigned* key2 = (unsigned*)bump(p, (size_t)NS2*4);
  int* fslot2 = (int*)bump(p, (size_t)NS2*4);
  int* rank2  = (int*)bump(p, (size_t)NS2*4);
  int* mid2   = (int*)bump(p, (size_t)NS2*4);
  int* ue2a   = (int*)bump(p, (size_t)NS2*4);
  int* ue2b   = (int*)bump(p, (size_t)NS2*4);
  // 4 contiguous tables -> one 0xFF memset (tmin as unsigned, init = UINT_MAX)
  unsigned* tables = (unsigned*)bump(p, (size_t)4*TSIZE*4);
  unsigned* tkey1 = tables;
  unsigned* tmin1 = tables + TSIZE;
  unsigned* tkey2 = tables + 2*TSIZE;
  unsigned* tmin2 = tables + 3*TSIZE;

  hipMemsetAsync(tables, 0xFF, (size_t)4*TSIZE*4, stream);

  // ---- feature transpose to channel-last: t[pos][c] ----
  transpose32<<<dim3((3136+31)/32, (256+31)/32), dim3(32,8), 0, stream>>>(f3, t3, 256, 3136);
  transpose32<<<dim3(( 784+31)/32, (512+31)/32), dim3(32,8), 0, stream>>>(f4, t4, 512,  784);
  transpose32<<<dim3(( 196+31)/32, (512+31)/32), dim3(32,8), 0, stream>>>(f5, t5, 512,  196);

  // ---- level 1: vf1 = [verts | perc1 | verts] ----
  pool1f<<<NV1, 320, 0, stream>>>(verts, t3, t4, t5, vf1);

  edge_insert<<<(NS1+255)/256, 256, 0, stream>>>(faces, NF1, NV1, tkey1, tmin1, key1);
  edge_first <<<(NS1+255)/256, 256, 0, stream>>>(key1, NS1, tkey1, tmin1, fslot1);
  scan_excl  <<<1, 1024, 0, stream>>>(fslot1, rank1, NS1);
  edge_mid   <<<(NS1+255)/256, 256, 0, stream>>>(key1, fslot1, rank1, NS1, NV1, mid1, ue1a, ue1b);
  new_faces  <<<(NF1+255)/256, 256, 0, stream>>>(faces, NF1, mid1, faces2);

  // ---- level 2: vf2 = [verts2(0:3) | perc2(3:1283) | s2(1283:2566)] ----
  subpool<<<NV2, 512, 0, stream>>>(vf1, P1, D1, NV1, ue1a, ue1b, t3, t4, t5,
                                   vf2, P2, vf2 + 1283, P2, vf2 + 3, P2);

  edge_insert<<<(NS2+255)/256, 256, 0, stream>>>(faces2, NF2, NV2, tkey2, tmin2, key2);
  edge_first <<<(NS2+255)/256, 256, 0, stream>>>(key2, NS2, tkey2, tmin2, fslot2);
  scan_excl  <<<1, 1024, 0, stream>>>(fslot2, rank2, NS2);
  edge_mid   <<<(NS2+255)/256, 256, 0, stream>>>(key2, fslot2, rank2, NS2, NV2, mid2, ue2a, ue2b);

  // ---- level 3: out = [perc3(0:1280) | s3(1280:3843)] ----
  subpool<<<NV3, 512, 0, stream>>>(vf2, P2, D2, NV2, ue2a, ue2b, t3, t4, t5,
                                   nullptr, 0, out + 1280, DOUT, out, DOUT);
}